// Round 6
// baseline (204.886 us; speedup 1.0000x reference)
//
#include <hip/hip_runtime.h>
#include <hip/hip_bf16.h>
#include <stdint.h>
#include <math.h>

#define NN 8192
#define DIN 512
#define HH 256
#define EE 262144
#define CAP 96
#define LN_EPS 1e-5f

typedef __attribute__((ext_vector_type(8))) short bf16x8;
typedef __attribute__((ext_vector_type(4))) short s16x4;
typedef __attribute__((ext_vector_type(4))) float f32x4;
typedef __attribute__((ext_vector_type(2))) float f32x2;

#if defined(__has_builtin)
#if __has_builtin(__builtin_amdgcn_cvt_pk_f32_fp8) && __has_builtin(__builtin_amdgcn_cvt_pk_fp8_f32)
#define HAVE_FP8_CVT 1
#endif
#endif

__device__ __forceinline__ short f2bf_bits(float x) {
    __hip_bfloat16 b = __float2bfloat16(x);
    return __builtin_bit_cast(short, b);
}
__device__ __forceinline__ float bf2f(short s) {
    uint32_t u = ((uint32_t)(uint16_t)s) << 16;
    return __builtin_bit_cast(float, u);
}
__device__ __forceinline__ void load16_lds(const void* g, void* l) {
    __builtin_amdgcn_global_load_lds((const __attribute__((address_space(1))) uint32_t*)g,
                                     (__attribute__((address_space(3))) uint32_t*)l, 16, 0, 0);
}

// ---- fp8 e4m3 (OCP) encode/decode: HW cvt on gfx950, software fallback otherwise ----
__device__ __forceinline__ uint8_t f2fp8(float x) {
#ifdef HAVE_FP8_CVT
    uint32_t p = __builtin_amdgcn_cvt_pk_fp8_f32(x, 0.f, 0u, false);
    return (uint8_t)(p & 0xFF);
#else
    uint8_t s = (x < 0.f) ? 0x80 : 0;
    float a = fabsf(x);
    if (!(a == a)) return 0x7F;
    if (a >= 448.f) return s | 0x7E;
    if (a < 0.0009765625f) return s;
    int e; float mf = frexpf(a, &e);
    int E = e + 6;
    if (E <= 0) { int q = (int)(a * 512.f + 0.5f); if (q >= 8) return s | 0x08; return s | (uint8_t)q; }
    int q = (int)(mf * 16.f + 0.5f);
    if (q >= 16) { q = 8; E++; }
    if (E > 15 || (E == 15 && q - 8 > 6)) return s | 0x7E;
    return s | (uint8_t)((E << 3) | (q - 8));
#endif
}
__device__ __forceinline__ void fp8x4_to_f32(uint32_t w, float* f) {
#ifdef HAVE_FP8_CVT
    f32x2 a = __builtin_amdgcn_cvt_pk_f32_fp8(w, false);
    f32x2 b = __builtin_amdgcn_cvt_pk_f32_fp8(w, true);
    f[0] = a[0]; f[1] = a[1]; f[2] = b[0]; f[3] = b[1];
#else
#pragma unroll
    for (int i = 0; i < 4; i++) {
        uint8_t bb = (w >> (8 * i)) & 0xFF;
        int s = bb >> 7, e = (bb >> 3) & 15, m = bb & 7;
        float v = e ? ldexpf((float)(8 + m), e - 10) : ldexpf((float)m, -9);
        f[i] = s ? -v : v;
    }
#endif
}

// ---------------- prep: zero accumulators/cnt/emb, convert W_in/W_gat to bf16 ----------------
// X is NOT converted here -- the input GEMM reg-stages f32 X directly (saves 24 MB).
#define NW1 (HH * DIN)
#define NW2 (2 * HH * HH)
#define ZCOUNT (2 * (2 * NN + HH) + NN)   // s1/s2/St x2 layers + cnt
__global__ __launch_bounds__(256) void prep(const float* __restrict__ W_in, __hip_bfloat16* __restrict__ Wb_in,
                                            const float* __restrict__ W_gat, __hip_bfloat16* __restrict__ Wgb,
                                            float* __restrict__ zbase, float* __restrict__ emb) {
    int gtid = blockIdx.x * 256 + threadIdx.x;   // grid = 256 blocks -> 65536 threads
    if (gtid < ZCOUNT) ((int*)zbase)[gtid] = 0;
    if (gtid < HH) emb[gtid] = 0.f;
    int q = gtid * 4;                            // q < NW1+NW2 = 262144 for all threads
    const float* x;
    __hip_bfloat16* y;
    int b;
    if (q < NW1) { x = W_in; y = Wb_in; b = q; }
    else { x = W_gat; y = Wgb; b = q - NW1; }
    float4 v = *(const float4*)(x + b);
    s16x4 s = { f2bf_bits(v.x), f2bf_bits(v.y), f2bf_bits(v.z), f2bf_bits(v.w) };
    *(s16x4*)((short*)y + b) = s;
}

// ---------------- merged: input GEMM (h = X @ W_in^T + b_in, f32 A reg-staged) + edge bucketing ----------------
#define GEMM_BLOCKS 512   // (HH/64) x (NN/64) = 4 x 128
__global__ __launch_bounds__(256) void gemm_in_fill(const float* __restrict__ X,
                                                    const __hip_bfloat16* __restrict__ B,
                                                    const float* __restrict__ bias,
                                                    __hip_bfloat16* __restrict__ Cb,
                                                    const int* __restrict__ src, const int* __restrict__ tgt,
                                                    int* __restrict__ cnt, int* __restrict__ buck) {
    __shared__ __hip_bfloat16 As[64 * 32];
    __shared__ __hip_bfloat16 Bs[64 * 32];
    const int bid = blockIdx.x;
    if (bid >= GEMM_BLOCKS) {
        // ---- edge bucketing: 512 blocks x 256 threads x 2 edges = EE exactly ----
        int k = ((bid - GEMM_BLOCKS) * 256 + threadIdx.x) * 2;
        int2 sv = *(const int2*)(src + k);
        int2 tv = *(const int2*)(tgt + k);
        int p = atomicAdd(&cnt[sv.x], 1);
        if (p < CAP) buck[sv.x * CAP + p] = tv.x;
        p = atomicAdd(&cnt[sv.y], 1);
        if (p < CAP) buck[sv.y * CAP + p] = tv.y;
        return;
    }
    const int tid = threadIdx.x;
    const int row0 = (bid >> 2) * 64, col0 = (bid & 3) * 64;
    const int w = tid >> 6, l = tid & 63;
    const int quad = l >> 4, r = l & 15;
    const int mh = (w & 1) * 32, nh = (w >> 1) * 32;
    f32x4 acc[2][2] = {};

    const int srow = tid >> 2, scol = (tid & 3) * 8;
    const float* gA = X + (size_t)(row0 + srow) * DIN + scol;
    const __hip_bfloat16* gB = B + (size_t)(col0 + srow) * DIN + scol;
    __hip_bfloat16* lB = &Bs[tid * 8];

    for (int k0 = 0; k0 < DIN; k0 += 32) {
        float4 a0 = *(const float4*)(gA + k0);
        float4 a1 = *(const float4*)(gA + k0 + 4);
        load16_lds(gB + k0, lB);
        bf16x8 av;
        av[0] = f2bf_bits(a0.x); av[1] = f2bf_bits(a0.y);
        av[2] = f2bf_bits(a0.z); av[3] = f2bf_bits(a0.w);
        av[4] = f2bf_bits(a1.x); av[5] = f2bf_bits(a1.y);
        av[6] = f2bf_bits(a1.z); av[7] = f2bf_bits(a1.w);
        *(bf16x8*)&As[tid * 8] = av;
        __syncthreads();
        bf16x8 aF[2], bF[2];
#pragma unroll
        for (int mi = 0; mi < 2; mi++)
            aF[mi] = *(const bf16x8*)&As[(mh + mi * 16 + r) * 32 + quad * 8];
#pragma unroll
        for (int ni = 0; ni < 2; ni++)
            bF[ni] = *(const bf16x8*)&Bs[(nh + ni * 16 + r) * 32 + quad * 8];
#pragma unroll
        for (int mi = 0; mi < 2; mi++)
#pragma unroll
            for (int ni = 0; ni < 2; ni++)
                acc[mi][ni] = __builtin_amdgcn_mfma_f32_16x16x32_bf16(aF[mi], bF[ni], acc[mi][ni], 0, 0, 0);
        __syncthreads();
    }

#pragma unroll
    for (int mi = 0; mi < 2; mi++)
#pragma unroll
        for (int ni = 0; ni < 2; ni++) {
            int gcol = col0 + nh + ni * 16 + r;
            float bv = bias[gcol];
#pragma unroll
            for (int reg = 0; reg < 4; reg++) {
                int grow = row0 + mh + mi * 16 + quad * 4 + reg;
                Cb[(size_t)grow * HH + gcol] = __float2bfloat16(acc[mi][ni][reg] + bv);
            }
        }
}

// ---------------- layer GEMM + fused score epilogue; C stored as fp8 e4m3 ----------------
__global__ __launch_bounds__(256) void gemm_bb_score(const __hip_bfloat16* __restrict__ A,
                                                     const __hip_bfloat16* __restrict__ B,
                                                     uint8_t* __restrict__ C8,
                                                     const float* __restrict__ ag1,
                                                     const float* __restrict__ ag2,
                                                     float* __restrict__ s1, float* __restrict__ s2,
                                                     float* __restrict__ St,
                                                     int Nc, int K) {
    __shared__ __hip_bfloat16 As[64 * 32];
    __shared__ __hip_bfloat16 Bs[64 * 32];
    const int tid = threadIdx.x;
    const int row0 = blockIdx.y * 64, col0 = blockIdx.x * 64;
    const int w = tid >> 6, l = tid & 63;
    const int quad = l >> 4, r = l & 15;
    const int mh = (w & 1) * 32, nh = (w >> 1) * 32;
    f32x4 acc[2][2] = {};

    const int srow = tid >> 2, scol = (tid & 3) * 8;
    const __hip_bfloat16* gA = A + (size_t)(row0 + srow) * K + scol;
    const __hip_bfloat16* gB = B + (size_t)(col0 + srow) * K + scol;
    __hip_bfloat16* lA = &As[tid * 8];
    __hip_bfloat16* lB = &Bs[tid * 8];

    for (int k0 = 0; k0 < K; k0 += 32) {
        load16_lds(gA + k0, lA);
        load16_lds(gB + k0, lB);
        __syncthreads();
        bf16x8 aF[2], bF[2];
#pragma unroll
        for (int mi = 0; mi < 2; mi++)
            aF[mi] = *(const bf16x8*)&As[(mh + mi * 16 + r) * 32 + quad * 8];
#pragma unroll
        for (int ni = 0; ni < 2; ni++)
            bF[ni] = *(const bf16x8*)&Bs[(nh + ni * 16 + r) * 32 + quad * 8];
#pragma unroll
        for (int mi = 0; mi < 2; mi++)
#pragma unroll
            for (int ni = 0; ni < 2; ni++)
                acc[mi][ni] = __builtin_amdgcn_mfma_f32_16x16x32_bf16(aF[mi], bF[ni], acc[mi][ni], 0, 0, 0);
        __syncthreads();
    }

#pragma unroll
    for (int mi = 0; mi < 2; mi++)
#pragma unroll
        for (int ni = 0; ni < 2; ni++) {
            int gcol = col0 + nh + ni * 16 + r;
#pragma unroll
            for (int reg = 0; reg < 4; reg++) {
                int grow = row0 + mh + mi * 16 + quad * 4 + reg;
                C8[(size_t)grow * Nc + gcol] = f2fp8(acc[mi][ni][reg]);
            }
        }

    float a1v[2], a2v[2];
#pragma unroll
    for (int ni = 0; ni < 2; ni++) {
        int gcol = col0 + nh + ni * 16 + r;
        a1v[ni] = ag1[gcol];
        a2v[ni] = ag2[gcol];
    }
#pragma unroll
    for (int mi = 0; mi < 2; mi++)
#pragma unroll
        for (int reg = 0; reg < 4; reg++) {
            float p1 = acc[mi][0][reg] * a1v[0] + acc[mi][1][reg] * a1v[1];
            float p2 = acc[mi][0][reg] * a2v[0] + acc[mi][1][reg] * a2v[1];
#pragma unroll
            for (int off = 1; off <= 8; off <<= 1) {
                p1 += __shfl_xor(p1, off);
                p2 += __shfl_xor(p2, off);
            }
            if (r == 0) {
                int grow = row0 + mh + mi * 16 + quad * 4 + reg;
                atomicAdd(&s1[grow], p1);
                atomicAdd(&s2[grow], p2);
            }
        }
#pragma unroll
    for (int ni = 0; ni < 2; ni++) {
        float pS = 0.f;
#pragma unroll
        for (int mi = 0; mi < 2; mi++)
#pragma unroll
            for (int reg = 0; reg < 4; reg++) pS += acc[mi][ni][reg];
        pS += __shfl_xor(pS, 16);
        pS += __shfl_xor(pS, 32);
        if (quad == 0) atomicAdd(&St[col0 + nh + ni * 16 + r], pS);
    }
}

// ---------------- wave-per-row GAT (R4 gather loop, unchanged); last layer fuses gated pooling ----------------
// lane = 64 lanes; half = lane>>5 processes even/odd edges; lane owns channels 8*(lane&31)..+7
__global__ __launch_bounds__(256) void gat_row(const __hip_bfloat16* __restrict__ hprev,
                                               const uint8_t* __restrict__ hw8,
                                               const int* __restrict__ cnt, const int* __restrict__ buck,
                                               const float* __restrict__ s1, const float* __restrict__ s2,
                                               const float* __restrict__ St,
                                               const float* __restrict__ lng, const float* __restrict__ lnb,
                                               const float* __restrict__ W_pool, const float* __restrict__ b_pool,
                                               float* __restrict__ houtf, __hip_bfloat16* __restrict__ houtb,
                                               float* __restrict__ emb, int last) {
    __shared__ float emb_s[4][HH];
    const int wv = threadIdx.x >> 6, lane = threadIdx.x & 63;
    const int half = lane >> 5, sl = lane & 31;
    const int i = blockIdx.x * 4 + wv;
    const int deg = min(cnt[i], CAP);
    const int base = i * CAP;
    const float s1i = s1[i];

    float u[8] = {};
    float lsum = 0.f;

    for (int kb = 0; kb < deg; kb += 64) {
        int k = kb + lane;
        float wk = 0.f;
        int ck = 0;
        if (k < deg) {
            int j = buck[base + k];
            float e = s1i + s2[j];
            e = e > 0.f ? e : 0.2f * e;
            wk = __expf(e) - 1.f;
            ck = j;
        }
        lsum += wk;
        int nb = min(64, deg - kb);
        int npair = (nb + 1) >> 1;            // <= 32
        for (int jj = 0; jj < npair; jj += 8) {
            int cj[8];
            float wj[8];
#pragma unroll
            for (int p = 0; p < 8; p++) {
                int e2 = 2 * (jj + p) + half; // <= 63 always
                cj[p] = __shfl(ck, e2);
                wj[p] = __shfl(wk, e2);
            }
            uint2 hv[8];
#pragma unroll
            for (int p = 0; p < 8; p++)
                hv[p] = *(const uint2*)(hw8 + (size_t)cj[p] * HH + 8 * sl);
#pragma unroll
            for (int p = 0; p < 8; p++) {
                float f[8];
                fp8x4_to_f32(hv[p].x, f);
                fp8x4_to_f32(hv[p].y, f + 4);
#pragma unroll
                for (int q = 0; q < 8; q++) u[q] += wj[p] * f[q];
            }
        }
    }
    // combine even/odd halves (each lane pair (sl, sl+32) covers same channels)
#pragma unroll
    for (int q = 0; q < 8; q++) u[q] += __shfl_xor(u[q], 32);
    // lsum over all 64 lanes
#pragma unroll
    for (int off = 32; off; off >>= 1) lsum += __shfl_xor(lsum, off);
    const float inv = 1.f / ((float)NN + lsum);

    float4 Sa = *(const float4*)(St + 8 * sl);
    float4 Sb = *(const float4*)(St + 8 * sl + 4);
    float Sts[8] = { Sa.x, Sa.y, Sa.z, Sa.w, Sb.x, Sb.y, Sb.z, Sb.w };
    bf16x8 hp = *(const bf16x8*)((const short*)hprev + (size_t)i * HH + 8 * sl);
    float x[8];
    float part = 0.f;
#pragma unroll
    for (int q = 0; q < 8; q++) { x[q] = bf2f(hp[q]) + (Sts[q] + u[q]) * inv; part += x[q]; }
    // 32-lane butterfly: each half independently sums all 256 channels
#pragma unroll
    for (int off = 16; off; off >>= 1) part += __shfl_xor(part, off);
    float mu = part * (1.f / HH);
    float d[8];
    float vs = 0.f;
#pragma unroll
    for (int q = 0; q < 8; q++) { d[q] = x[q] - mu; vs += d[q] * d[q]; }
#pragma unroll
    for (int off = 16; off; off >>= 1) vs += __shfl_xor(vs, off);
    float rstd = rsqrtf(vs * (1.f / HH) + LN_EPS);
    float4 ga = *(const float4*)(lng + 8 * sl);
    float4 gb = *(const float4*)(lng + 8 * sl + 4);
    float4 ba = *(const float4*)(lnb + 8 * sl);
    float4 bb = *(const float4*)(lnb + 8 * sl + 4);
    float gg[8] = { ga.x, ga.y, ga.z, ga.w, gb.x, gb.y, gb.z, gb.w };
    float bv[8] = { ba.x, ba.y, ba.z, ba.w, bb.x, bb.y, bb.z, bb.w };
    float y[8];
#pragma unroll
    for (int q = 0; q < 8; q++) {
        float t = d[q] * rstd * gg[q] + bv[q];
        y[q] = t > 0.f ? t : __expf(t) - 1.f;
    }

    // stores: half 0 writes channels [8sl..8sl+3], half 1 writes [8sl+4..8sl+7]
    const int co = 8 * sl + 4 * half;
    if (houtb) {
        s16x4 yv;
#pragma unroll
        for (int q = 0; q < 4; q++) yv[q] = f2bf_bits(y[4 * half + q]);
        *(s16x4*)((short*)houtb + (size_t)i * HH + co) = yv;
    }
    if (houtf) {
        float4 yf = { y[4 * half], y[4 * half + 1], y[4 * half + 2], y[4 * half + 3] };
        *(float4*)(houtf + (size_t)i * HH + co) = yf;
    }

    if (last) {
        // gate_i = sigmoid(y . W_pool + b_pool); fused pooling: emb += gate_i * y_i
        float4 wa = *(const float4*)(W_pool + 8 * sl);
        float4 wb = *(const float4*)(W_pool + 8 * sl + 4);
        float wp[8] = { wa.x, wa.y, wa.z, wa.w, wb.x, wb.y, wb.z, wb.w };
        float p = 0.f;
#pragma unroll
        for (int q = 0; q < 8; q++) p += y[q] * wp[q];
#pragma unroll
        for (int off = 16; off; off >>= 1) p += __shfl_xor(p, off);
        float g = 1.f / (1.f + __expf(-(p + b_pool[0])));
        // per-wave slice into LDS (each channel written by exactly one lane per wave)
#pragma unroll
        for (int q = 0; q < 4; q++) emb_s[wv][co + q] = g * y[4 * half + q];
        __syncthreads();
        int c = threadIdx.x;   // 256 threads = HH channels
        float s = emb_s[0][c] + emb_s[1][c] + emb_s[2][c] + emb_s[3][c];
        atomicAdd(&emb[c], s);
    }
}

extern "C" void kernel_launch(void* const* d_in, const int* in_sizes, int n_in,
                              void* d_out, int out_size, void* d_ws, size_t ws_size,
                              hipStream_t stream) {
    const float* X      = (const float*)d_in[0];
    const int*   ei     = (const int*)d_in[1];
    const float* W_in   = (const float*)d_in[2];
    const float* b_in   = (const float*)d_in[3];
    const float* W_gat  = (const float*)d_in[4];
    const float* a_gat  = (const float*)d_in[5];
    const float* ln_g   = (const float*)d_in[6];
    const float* ln_b   = (const float*)d_in[7];
    const float* W_pool = (const float*)d_in[8];
    const float* b_pool = (const float*)d_in[9];
    float* out = (float*)d_out;

    // ws layout: bf16/fp8 region, then zero-init fp32/int block, then buckets
    __hip_bfloat16* hb    = (__hip_bfloat16*)d_ws;            // NN*HH bf16
    uint8_t*        hw8   = (uint8_t*)(hb + (size_t)NN * HH); // NN*HH fp8
    __hip_bfloat16* Wb_in = (__hip_bfloat16*)(hw8 + (size_t)NN * HH); // HH*DIN
    __hip_bfloat16* Wgb   = Wb_in + (size_t)HH * DIN;         // 2*HH*HH
    float* zbase = (float*)(Wgb + (size_t)2 * HH * HH);
    float* s1_0 = zbase;                 // NN
    float* s2_0 = s1_0 + NN;             // NN
    float* St_0 = s2_0 + NN;             // HH
    float* s1_1 = St_0 + HH;             // NN
    float* s2_1 = s1_1 + NN;             // NN
    float* St_1 = s2_1 + NN;             // HH
    int* cnt  = (int*)(St_1 + HH);       // NN  (zeroed in prep)
    int* buck = (int*)(cnt + NN);        // NN*CAP

    const int* src = ei;
    const int* tgt = ei + EE;
    float* emb = out + (size_t)NN * HH;

    // 1) prep: zero + weight bf16 conversions
    prep<<<256, 256, 0, stream>>>(W_in, Wb_in, W_gat, Wgb, zbase, emb);

    // 2) h = X @ W_in^T + b_in (f32 A reg-staged)  ||  edge bucketing (blocks >= 512)
    gemm_in_fill<<<GEMM_BLOCKS + EE / 512, 256, 0, stream>>>(X, Wb_in, b_in, hb, src, tgt, cnt, buck);

    for (int ll = 0; ll < 2; ll++) {
        float* s1 = ll ? s1_1 : s1_0;
        float* s2 = ll ? s2_1 : s2_0;
        float* St = ll ? St_1 : St_0;
        const float* ag = a_gat + (size_t)ll * 2 * HH;
        // 3/5) hw = h @ W_gat[l]^T (fp8 out) + score partials
        gemm_bb_score<<<dim3(HH / 64, NN / 64), 256, 0, stream>>>(hb, Wgb + (size_t)ll * HH * HH, hw8,
                                                                  ag, ag + HH, s1, s2, St, HH, HH);
        // 4/6) aggregation + LN + ELU (+ fused gate/pool on last layer)
        gat_row<<<NN / 4, 256, 0, stream>>>(hb, hw8, cnt, buck, s1, s2, St,
                                            ln_g + (size_t)ll * HH, ln_b + (size_t)ll * HH,
                                            W_pool, b_pool,
                                            (ll == 1) ? out : nullptr,
                                            (ll == 0) ? hb : nullptr,
                                            emb, ll);
    }
}

// Round 7
// 203.640 us; speedup vs baseline: 1.0061x; 1.0061x over previous
//
#include <hip/hip_runtime.h>
#include <hip/hip_bf16.h>
#include <stdint.h>
#include <math.h>

#define NN 8192
#define DIN 512
#define HH 256
#define EE 262144
#define CAP 96
#define LN_EPS 1e-5f

typedef __attribute__((ext_vector_type(8))) short bf16x8;
typedef __attribute__((ext_vector_type(4))) short s16x4;
typedef __attribute__((ext_vector_type(4))) float f32x4;
typedef __attribute__((ext_vector_type(2))) float f32x2;

#if defined(__has_builtin)
#if __has_builtin(__builtin_amdgcn_cvt_pk_f32_fp8) && __has_builtin(__builtin_amdgcn_cvt_pk_fp8_f32)
#define HAVE_FP8_CVT 1
#endif
#endif

__device__ __forceinline__ short f2bf_bits(float x) {
    __hip_bfloat16 b = __float2bfloat16(x);
    return __builtin_bit_cast(short, b);
}
__device__ __forceinline__ float bf2f(short s) {
    uint32_t u = ((uint32_t)(uint16_t)s) << 16;
    return __builtin_bit_cast(float, u);
}
__device__ __forceinline__ void load16_lds(const void* g, void* l) {
    __builtin_amdgcn_global_load_lds((const __attribute__((address_space(1))) uint32_t*)g,
                                     (__attribute__((address_space(3))) uint32_t*)l, 16, 0, 0);
}

// ---- fp8 e4m3 (OCP) encode/decode: HW cvt on gfx950, software fallback otherwise ----
__device__ __forceinline__ uint8_t f2fp8(float x) {
#ifdef HAVE_FP8_CVT
    uint32_t p = __builtin_amdgcn_cvt_pk_fp8_f32(x, 0.f, 0u, false);
    return (uint8_t)(p & 0xFF);
#else
    uint8_t s = (x < 0.f) ? 0x80 : 0;
    float a = fabsf(x);
    if (!(a == a)) return 0x7F;
    if (a >= 448.f) return s | 0x7E;
    if (a < 0.0009765625f) return s;
    int e; float mf = frexpf(a, &e);
    int E = e + 6;
    if (E <= 0) { int q = (int)(a * 512.f + 0.5f); if (q >= 8) return s | 0x08; return s | (uint8_t)q; }
    int q = (int)(mf * 16.f + 0.5f);
    if (q >= 16) { q = 8; E++; }
    if (E > 15 || (E == 15 && q - 8 > 6)) return s | 0x7E;
    return s | (uint8_t)((E << 3) | (q - 8));
#endif
}
__device__ __forceinline__ void fp8x4_to_f32(uint32_t w, float* f) {
#ifdef HAVE_FP8_CVT
    f32x2 a = __builtin_amdgcn_cvt_pk_f32_fp8(w, false);
    f32x2 b = __builtin_amdgcn_cvt_pk_f32_fp8(w, true);
    f[0] = a[0]; f[1] = a[1]; f[2] = b[0]; f[3] = b[1];
#else
#pragma unroll
    for (int i = 0; i < 4; i++) {
        uint8_t bb = (w >> (8 * i)) & 0xFF;
        int s = bb >> 7, e = (bb >> 3) & 15, m = bb & 7;
        float v = e ? ldexpf((float)(8 + m), e - 10) : ldexpf((float)m, -9);
        f[i] = s ? -v : v;
    }
#endif
}

// ---------------- prep: zero accumulators/cnt/emb, convert W_in/W_gat to bf16 ----------------
// X is NOT converted here -- the input GEMM reg-stages f32 X directly (saves 24 MB).
#define NW1 (HH * DIN)
#define NW2 (2 * HH * HH)
#define ZCOUNT (2 * (2 * NN + HH) + NN)   // s1/s2/St x2 layers + cnt
__global__ __launch_bounds__(256) void prep(const float* __restrict__ W_in, __hip_bfloat16* __restrict__ Wb_in,
                                            const float* __restrict__ W_gat, __hip_bfloat16* __restrict__ Wgb,
                                            float* __restrict__ zbase, float* __restrict__ emb) {
    int gtid = blockIdx.x * 256 + threadIdx.x;   // grid = 256 blocks -> 65536 threads
    if (gtid < ZCOUNT) ((int*)zbase)[gtid] = 0;
    if (gtid < HH) emb[gtid] = 0.f;
    int q = gtid * 4;                            // q < NW1+NW2 = 262144 for all threads
    const float* x;
    __hip_bfloat16* y;
    int b;
    if (q < NW1) { x = W_in; y = Wb_in; b = q; }
    else { x = W_gat; y = Wgb; b = q - NW1; }
    float4 v = *(const float4*)(x + b);
    s16x4 s = { f2bf_bits(v.x), f2bf_bits(v.y), f2bf_bits(v.z), f2bf_bits(v.w) };
    *(s16x4*)((short*)y + b) = s;
}

// ---------------- merged: input GEMM (h = X @ W_in^T + b_in, f32 A reg-staged) + edge bucketing ----------------
#define GEMM_BLOCKS 512   // (HH/64) x (NN/64) = 4 x 128
__global__ __launch_bounds__(256) void gemm_in_fill(const float* __restrict__ X,
                                                    const __hip_bfloat16* __restrict__ B,
                                                    const float* __restrict__ bias,
                                                    __hip_bfloat16* __restrict__ Cb,
                                                    const int* __restrict__ src, const int* __restrict__ tgt,
                                                    int* __restrict__ cnt, int* __restrict__ buck) {
    __shared__ __hip_bfloat16 As[64 * 32];
    __shared__ __hip_bfloat16 Bs[64 * 32];
    const int bid = blockIdx.x;
    if (bid >= GEMM_BLOCKS) {
        // ---- edge bucketing: 512 blocks x 256 threads x 2 edges = EE exactly ----
        int k = ((bid - GEMM_BLOCKS) * 256 + threadIdx.x) * 2;
        int2 sv = *(const int2*)(src + k);
        int2 tv = *(const int2*)(tgt + k);
        int p = atomicAdd(&cnt[sv.x], 1);
        if (p < CAP) buck[sv.x * CAP + p] = tv.x;
        p = atomicAdd(&cnt[sv.y], 1);
        if (p < CAP) buck[sv.y * CAP + p] = tv.y;
        return;
    }
    const int tid = threadIdx.x;
    const int row0 = (bid >> 2) * 64, col0 = (bid & 3) * 64;
    const int w = tid >> 6, l = tid & 63;
    const int quad = l >> 4, r = l & 15;
    const int mh = (w & 1) * 32, nh = (w >> 1) * 32;
    f32x4 acc[2][2] = {};

    const int srow = tid >> 2, scol = (tid & 3) * 8;
    const float* gA = X + (size_t)(row0 + srow) * DIN + scol;
    const __hip_bfloat16* gB = B + (size_t)(col0 + srow) * DIN + scol;
    __hip_bfloat16* lB = &Bs[tid * 8];

    for (int k0 = 0; k0 < DIN; k0 += 32) {
        float4 a0 = *(const float4*)(gA + k0);
        float4 a1 = *(const float4*)(gA + k0 + 4);
        load16_lds(gB + k0, lB);
        bf16x8 av;
        av[0] = f2bf_bits(a0.x); av[1] = f2bf_bits(a0.y);
        av[2] = f2bf_bits(a0.z); av[3] = f2bf_bits(a0.w);
        av[4] = f2bf_bits(a1.x); av[5] = f2bf_bits(a1.y);
        av[6] = f2bf_bits(a1.z); av[7] = f2bf_bits(a1.w);
        *(bf16x8*)&As[tid * 8] = av;
        __syncthreads();
        bf16x8 aF[2], bF[2];
#pragma unroll
        for (int mi = 0; mi < 2; mi++)
            aF[mi] = *(const bf16x8*)&As[(mh + mi * 16 + r) * 32 + quad * 8];
#pragma unroll
        for (int ni = 0; ni < 2; ni++)
            bF[ni] = *(const bf16x8*)&Bs[(nh + ni * 16 + r) * 32 + quad * 8];
#pragma unroll
        for (int mi = 0; mi < 2; mi++)
#pragma unroll
            for (int ni = 0; ni < 2; ni++)
                acc[mi][ni] = __builtin_amdgcn_mfma_f32_16x16x32_bf16(aF[mi], bF[ni], acc[mi][ni], 0, 0, 0);
        __syncthreads();
    }

#pragma unroll
    for (int mi = 0; mi < 2; mi++)
#pragma unroll
        for (int ni = 0; ni < 2; ni++) {
            int gcol = col0 + nh + ni * 16 + r;
            float bv = bias[gcol];
#pragma unroll
            for (int reg = 0; reg < 4; reg++) {
                int grow = row0 + mh + mi * 16 + quad * 4 + reg;
                Cb[(size_t)grow * HH + gcol] = __float2bfloat16(acc[mi][ni][reg] + bv);
            }
        }
}

// ---------------- layer GEMM + fused score epilogue; C stored as fp8 e4m3 ----------------
__global__ __launch_bounds__(256) void gemm_bb_score(const __hip_bfloat16* __restrict__ A,
                                                     const __hip_bfloat16* __restrict__ B,
                                                     uint8_t* __restrict__ C8,
                                                     const float* __restrict__ ag1,
                                                     const float* __restrict__ ag2,
                                                     float* __restrict__ s1, float* __restrict__ s2,
                                                     float* __restrict__ St,
                                                     int Nc, int K) {
    __shared__ __hip_bfloat16 As[64 * 32];
    __shared__ __hip_bfloat16 Bs[64 * 32];
    const int tid = threadIdx.x;
    const int row0 = blockIdx.y * 64, col0 = blockIdx.x * 64;
    const int w = tid >> 6, l = tid & 63;
    const int quad = l >> 4, r = l & 15;
    const int mh = (w & 1) * 32, nh = (w >> 1) * 32;
    f32x4 acc[2][2] = {};

    const int srow = tid >> 2, scol = (tid & 3) * 8;
    const __hip_bfloat16* gA = A + (size_t)(row0 + srow) * K + scol;
    const __hip_bfloat16* gB = B + (size_t)(col0 + srow) * K + scol;
    __hip_bfloat16* lA = &As[tid * 8];
    __hip_bfloat16* lB = &Bs[tid * 8];

    for (int k0 = 0; k0 < K; k0 += 32) {
        load16_lds(gA + k0, lA);
        load16_lds(gB + k0, lB);
        __syncthreads();
        bf16x8 aF[2], bF[2];
#pragma unroll
        for (int mi = 0; mi < 2; mi++)
            aF[mi] = *(const bf16x8*)&As[(mh + mi * 16 + r) * 32 + quad * 8];
#pragma unroll
        for (int ni = 0; ni < 2; ni++)
            bF[ni] = *(const bf16x8*)&Bs[(nh + ni * 16 + r) * 32 + quad * 8];
#pragma unroll
        for (int mi = 0; mi < 2; mi++)
#pragma unroll
            for (int ni = 0; ni < 2; ni++)
                acc[mi][ni] = __builtin_amdgcn_mfma_f32_16x16x32_bf16(aF[mi], bF[ni], acc[mi][ni], 0, 0, 0);
        __syncthreads();
    }

#pragma unroll
    for (int mi = 0; mi < 2; mi++)
#pragma unroll
        for (int ni = 0; ni < 2; ni++) {
            int gcol = col0 + nh + ni * 16 + r;
#pragma unroll
            for (int reg = 0; reg < 4; reg++) {
                int grow = row0 + mh + mi * 16 + quad * 4 + reg;
                C8[(size_t)grow * Nc + gcol] = f2fp8(acc[mi][ni][reg]);
            }
        }

    float a1v[2], a2v[2];
#pragma unroll
    for (int ni = 0; ni < 2; ni++) {
        int gcol = col0 + nh + ni * 16 + r;
        a1v[ni] = ag1[gcol];
        a2v[ni] = ag2[gcol];
    }
#pragma unroll
    for (int mi = 0; mi < 2; mi++)
#pragma unroll
        for (int reg = 0; reg < 4; reg++) {
            float p1 = acc[mi][0][reg] * a1v[0] + acc[mi][1][reg] * a1v[1];
            float p2 = acc[mi][0][reg] * a2v[0] + acc[mi][1][reg] * a2v[1];
#pragma unroll
            for (int off = 1; off <= 8; off <<= 1) {
                p1 += __shfl_xor(p1, off);
                p2 += __shfl_xor(p2, off);
            }
            if (r == 0) {
                int grow = row0 + mh + mi * 16 + quad * 4 + reg;
                atomicAdd(&s1[grow], p1);
                atomicAdd(&s2[grow], p2);
            }
        }
#pragma unroll
    for (int ni = 0; ni < 2; ni++) {
        float pS = 0.f;
#pragma unroll
        for (int mi = 0; mi < 2; mi++)
#pragma unroll
            for (int reg = 0; reg < 4; reg++) pS += acc[mi][ni][reg];
        pS += __shfl_xor(pS, 16);
        pS += __shfl_xor(pS, 32);
        if (quad == 0) atomicAdd(&St[col0 + nh + ni * 16 + r], pS);
    }
}

// ---------------- wave-per-row GAT (R4 gather loop, unchanged); last layer fuses gated pooling ----------------
// lane = 64 lanes; half = lane>>5 processes even/odd edges; lane owns channels 8*(lane&31)..+7
__global__ __launch_bounds__(256) void gat_row(const __hip_bfloat16* __restrict__ hprev,
                                               const uint8_t* __restrict__ hw8,
                                               const int* __restrict__ cnt, const int* __restrict__ buck,
                                               const float* __restrict__ s1, const float* __restrict__ s2,
                                               const float* __restrict__ St,
                                               const float* __restrict__ lng, const float* __restrict__ lnb,
                                               const float* __restrict__ W_pool, const float* __restrict__ b_pool,
                                               float* __restrict__ houtf, __hip_bfloat16* __restrict__ houtb,
                                               float* __restrict__ emb, int last) {
    __shared__ float emb_s[4][HH];
    const int wv = threadIdx.x >> 6, lane = threadIdx.x & 63;
    const int half = lane >> 5, sl = lane & 31;
    const int i = blockIdx.x * 4 + wv;
    const int deg = min(cnt[i], CAP);
    const int base = i * CAP;
    const float s1i = s1[i];

    float u[8] = {};
    float lsum = 0.f;

    for (int kb = 0; kb < deg; kb += 64) {
        int k = kb + lane;
        float wk = 0.f;
        int ck = 0;
        if (k < deg) {
            int j = buck[base + k];
            float e = s1i + s2[j];
            e = e > 0.f ? e : 0.2f * e;
            wk = __expf(e) - 1.f;
            ck = j;
        }
        lsum += wk;
        int nb = min(64, deg - kb);
        int npair = (nb + 1) >> 1;            // <= 32
        for (int jj = 0; jj < npair; jj += 8) {
            int cj[8];
            float wj[8];
#pragma unroll
            for (int p = 0; p < 8; p++) {
                int e2 = 2 * (jj + p) + half; // <= 63 always
                cj[p] = __shfl(ck, e2);
                wj[p] = __shfl(wk, e2);
            }
            uint2 hv[8];
#pragma unroll
            for (int p = 0; p < 8; p++)
                hv[p] = *(const uint2*)(hw8 + (size_t)cj[p] * HH + 8 * sl);
#pragma unroll
            for (int p = 0; p < 8; p++) {
                float f[8];
                fp8x4_to_f32(hv[p].x, f);
                fp8x4_to_f32(hv[p].y, f + 4);
#pragma unroll
                for (int q = 0; q < 8; q++) u[q] += wj[p] * f[q];
            }
        }
    }
    // combine even/odd halves (each lane pair (sl, sl+32) covers same channels)
#pragma unroll
    for (int q = 0; q < 8; q++) u[q] += __shfl_xor(u[q], 32);
    // lsum over all 64 lanes
#pragma unroll
    for (int off = 32; off; off >>= 1) lsum += __shfl_xor(lsum, off);
    const float inv = 1.f / ((float)NN + lsum);

    float4 Sa = *(const float4*)(St + 8 * sl);
    float4 Sb = *(const float4*)(St + 8 * sl + 4);
    float Sts[8] = { Sa.x, Sa.y, Sa.z, Sa.w, Sb.x, Sb.y, Sb.z, Sb.w };
    bf16x8 hp = *(const bf16x8*)((const short*)hprev + (size_t)i * HH + 8 * sl);
    float x[8];
    float part = 0.f;
#pragma unroll
    for (int q = 0; q < 8; q++) { x[q] = bf2f(hp[q]) + (Sts[q] + u[q]) * inv; part += x[q]; }
    // 32-lane butterfly: each half independently sums all 256 channels
#pragma unroll
    for (int off = 16; off; off >>= 1) part += __shfl_xor(part, off);
    float mu = part * (1.f / HH);
    float d[8];
    float vs = 0.f;
#pragma unroll
    for (int q = 0; q < 8; q++) { d[q] = x[q] - mu; vs += d[q] * d[q]; }
#pragma unroll
    for (int off = 16; off; off >>= 1) vs += __shfl_xor(vs, off);
    float rstd = rsqrtf(vs * (1.f / HH) + LN_EPS);
    float4 ga = *(const float4*)(lng + 8 * sl);
    float4 gb = *(const float4*)(lng + 8 * sl + 4);
    float4 ba = *(const float4*)(lnb + 8 * sl);
    float4 bb = *(const float4*)(lnb + 8 * sl + 4);
    float gg[8] = { ga.x, ga.y, ga.z, ga.w, gb.x, gb.y, gb.z, gb.w };
    float bv[8] = { ba.x, ba.y, ba.z, ba.w, bb.x, bb.y, bb.z, bb.w };
    float y[8];
#pragma unroll
    for (int q = 0; q < 8; q++) {
        float t = d[q] * rstd * gg[q] + bv[q];
        y[q] = t > 0.f ? t : __expf(t) - 1.f;
    }

    // stores: half 0 writes channels [8sl..8sl+3], half 1 writes [8sl+4..8sl+7]
    const int co = 8 * sl + 4 * half;
    if (houtb) {
        s16x4 yv;
#pragma unroll
        for (int q = 0; q < 4; q++) yv[q] = f2bf_bits(y[4 * half + q]);
        *(s16x4*)((short*)houtb + (size_t)i * HH + co) = yv;
    }
    if (houtf) {
        float4 yf = { y[4 * half], y[4 * half + 1], y[4 * half + 2], y[4 * half + 3] };
        *(float4*)(houtf + (size_t)i * HH + co) = yf;
    }

    if (last) {
        // gate_i = sigmoid(y . W_pool + b_pool); fused pooling: emb += gate_i * y_i
        float4 wa = *(const float4*)(W_pool + 8 * sl);
        float4 wb = *(const float4*)(W_pool + 8 * sl + 4);
        float wp[8] = { wa.x, wa.y, wa.z, wa.w, wb.x, wb.y, wb.z, wb.w };
        float p = 0.f;
#pragma unroll
        for (int q = 0; q < 8; q++) p += y[q] * wp[q];
#pragma unroll
        for (int off = 16; off; off >>= 1) p += __shfl_xor(p, off);
        float g = 1.f / (1.f + __expf(-(p + b_pool[0])));
        // per-wave slice into LDS (each channel written by exactly one lane per wave)
#pragma unroll
        for (int q = 0; q < 4; q++) emb_s[wv][co + q] = g * y[4 * half + q];
        __syncthreads();
        int c = threadIdx.x;   // 256 threads = HH channels
        float s = emb_s[0][c] + emb_s[1][c] + emb_s[2][c] + emb_s[3][c];
        atomicAdd(&emb[c], s);
    }
}

extern "C" void kernel_launch(void* const* d_in, const int* in_sizes, int n_in,
                              void* d_out, int out_size, void* d_ws, size_t ws_size,
                              hipStream_t stream) {
    const float* X      = (const float*)d_in[0];
    const int*   ei     = (const int*)d_in[1];
    const float* W_in   = (const float*)d_in[2];
    const float* b_in   = (const float*)d_in[3];
    const float* W_gat  = (const float*)d_in[4];
    const float* a_gat  = (const float*)d_in[5];
    const float* ln_g   = (const float*)d_in[6];
    const float* ln_b   = (const float*)d_in[7];
    const float* W_pool = (const float*)d_in[8];
    const float* b_pool = (const float*)d_in[9];
    float* out = (float*)d_out;

    // ws layout: bf16/fp8 region, then zero-init fp32/int block, then buckets
    __hip_bfloat16* hb    = (__hip_bfloat16*)d_ws;            // NN*HH bf16
    uint8_t*        hw8   = (uint8_t*)(hb + (size_t)NN * HH); // NN*HH fp8
    __hip_bfloat16* Wb_in = (__hip_bfloat16*)(hw8 + (size_t)NN * HH); // HH*DIN
    __hip_bfloat16* Wgb   = Wb_in + (size_t)HH * DIN;         // 2*HH*HH
    float* zbase = (float*)(Wgb + (size_t)2 * HH * HH);
    float* s1_0 = zbase;                 // NN
    float* s2_0 = s1_0 + NN;             // NN
    float* St_0 = s2_0 + NN;             // HH
    float* s1_1 = St_0 + HH;             // NN
    float* s2_1 = s1_1 + NN;             // NN
    float* St_1 = s2_1 + NN;             // HH
    int* cnt  = (int*)(St_1 + HH);       // NN  (zeroed in prep)
    int* buck = (int*)(cnt + NN);        // NN*CAP

    const int* src = ei;
    const int* tgt = ei + EE;
    float* emb = out + (size_t)NN * HH;

    // 1) prep: zero + weight bf16 conversions
    prep<<<256, 256, 0, stream>>>(W_in, Wb_in, W_gat, Wgb, zbase, emb);

    // 2) h = X @ W_in^T + b_in (f32 A reg-staged)  ||  edge bucketing (blocks >= 512)
    gemm_in_fill<<<GEMM_BLOCKS + EE / 512, 256, 0, stream>>>(X, Wb_in, b_in, hb, src, tgt, cnt, buck);

    for (int ll = 0; ll < 2; ll++) {
        float* s1 = ll ? s1_1 : s1_0;
        float* s2 = ll ? s2_1 : s2_0;
        float* St = ll ? St_1 : St_0;
        const float* ag = a_gat + (size_t)ll * 2 * HH;
        // 3/5) hw = h @ W_gat[l]^T (fp8 out) + score partials
        gemm_bb_score<<<dim3(HH / 64, NN / 64), 256, 0, stream>>>(hb, Wgb + (size_t)ll * HH * HH, hw8,
                                                                  ag, ag + HH, s1, s2, St, HH, HH);
        // 4/6) aggregation + LN + ELU (+ fused gate/pool on last layer)
        gat_row<<<NN / 4, 256, 0, stream>>>(hb, hw8, cnt, buck, s1, s2, St,
                                            ln_g + (size_t)ll * HH, ln_b + (size_t)ll * HH,
                                            W_pool, b_pool,
                                            (ll == 1) ? out : nullptr,
                                            (ll == 0) ? hb : nullptr,
                                            emb, ll);
    }
}

// Round 8
// 169.333 us; speedup vs baseline: 1.2100x; 1.2026x over previous
//
#include <hip/hip_runtime.h>
#include <hip/hip_bf16.h>
#include <stdint.h>
#include <math.h>

#define NN 8192
#define DIN 512
#define HH 256
#define EE 262144
#define CAP 96
#define LN_EPS 1e-5f

typedef __attribute__((ext_vector_type(8))) short bf16x8;
typedef __attribute__((ext_vector_type(4))) short s16x4;
typedef __attribute__((ext_vector_type(4))) float f32x4;
typedef __attribute__((ext_vector_type(2))) float f32x2;

#if defined(__has_builtin)
#if __has_builtin(__builtin_amdgcn_cvt_pk_f32_fp8) && __has_builtin(__builtin_amdgcn_cvt_pk_fp8_f32)
#define HAVE_FP8_CVT 1
#endif
#endif

__device__ __forceinline__ short f2bf_bits(float x) {
    __hip_bfloat16 b = __float2bfloat16(x);
    return __builtin_bit_cast(short, b);
}
__device__ __forceinline__ float bf2f(short s) {
    uint32_t u = ((uint32_t)(uint16_t)s) << 16;
    return __builtin_bit_cast(float, u);
}
__device__ __forceinline__ void load16_lds(const void* g, void* l) {
    __builtin_amdgcn_global_load_lds((const __attribute__((address_space(1))) uint32_t*)g,
                                     (__attribute__((address_space(3))) uint32_t*)l, 16, 0, 0);
}

// ---- fp8 e4m3 (OCP) encode/decode: HW cvt on gfx950, software fallback otherwise ----
__device__ __forceinline__ uint8_t f2fp8(float x) {
#ifdef HAVE_FP8_CVT
    uint32_t p = __builtin_amdgcn_cvt_pk_fp8_f32(x, 0.f, 0u, false);
    return (uint8_t)(p & 0xFF);
#else
    uint8_t s = (x < 0.f) ? 0x80 : 0;
    float a = fabsf(x);
    if (!(a == a)) return 0x7F;
    if (a >= 448.f) return s | 0x7E;
    if (a < 0.0009765625f) return s;
    int e; float mf = frexpf(a, &e);
    int E = e + 6;
    if (E <= 0) { int q = (int)(a * 512.f + 0.5f); if (q >= 8) return s | 0x08; return s | (uint8_t)q; }
    int q = (int)(mf * 16.f + 0.5f);
    if (q >= 16) { q = 8; E++; }
    if (E > 15 || (E == 15 && q - 8 > 6)) return s | 0x7E;
    return s | (uint8_t)((E << 3) | (q - 8));
#endif
}
__device__ __forceinline__ void fp8x4_to_f32(uint32_t w, float* f) {
#ifdef HAVE_FP8_CVT
    f32x2 a = __builtin_amdgcn_cvt_pk_f32_fp8(w, false);
    f32x2 b = __builtin_amdgcn_cvt_pk_f32_fp8(w, true);
    f[0] = a[0]; f[1] = a[1]; f[2] = b[0]; f[3] = b[1];
#else
#pragma unroll
    for (int i = 0; i < 4; i++) {
        uint8_t bb = (w >> (8 * i)) & 0xFF;
        int s = bb >> 7, e = (bb >> 3) & 15, m = bb & 7;
        float v = e ? ldexpf((float)(8 + m), e - 10) : ldexpf((float)m, -9);
        f[i] = s ? -v : v;
    }
#endif
}

// ---------------- prep: zero accumulators/cnt/emb, convert W_in/W_gat to bf16 ----------------
// X is NOT converted here -- the input GEMM reg-stages f32 X directly (saves 24 MB).
#define NW1 (HH * DIN)
#define NW2 (2 * HH * HH)
#define ZCOUNT (2 * (2 * NN + HH) + NN)   // s1/s2/St x2 layers + cnt
__global__ __launch_bounds__(256) void prep(const float* __restrict__ W_in, __hip_bfloat16* __restrict__ Wb_in,
                                            const float* __restrict__ W_gat, __hip_bfloat16* __restrict__ Wgb,
                                            float* __restrict__ zbase, float* __restrict__ emb) {
    int gtid = blockIdx.x * 256 + threadIdx.x;   // grid = 256 blocks -> 65536 threads
    if (gtid < ZCOUNT) ((int*)zbase)[gtid] = 0;
    if (gtid < HH) emb[gtid] = 0.f;
    int q = gtid * 4;                            // q < NW1+NW2 = 262144 for all threads
    const float* x;
    __hip_bfloat16* y;
    int b;
    if (q < NW1) { x = W_in; y = Wb_in; b = q; }
    else { x = W_gat; y = Wgb; b = q - NW1; }
    float4 v = *(const float4*)(x + b);
    s16x4 s = { f2bf_bits(v.x), f2bf_bits(v.y), f2bf_bits(v.z), f2bf_bits(v.w) };
    *(s16x4*)((short*)y + b) = s;
}

// ---------------- merged: input GEMM (h = X @ W_in^T + b_in, f32 A reg-staged) + edge bucketing ----------------
#define GEMM_BLOCKS 512   // (HH/64) x (NN/64) = 4 x 128
__global__ __launch_bounds__(256) void gemm_in_fill(const float* __restrict__ X,
                                                    const __hip_bfloat16* __restrict__ B,
                                                    const float* __restrict__ bias,
                                                    __hip_bfloat16* __restrict__ Cb,
                                                    const int* __restrict__ src, const int* __restrict__ tgt,
                                                    int* __restrict__ cnt, int* __restrict__ buck) {
    __shared__ __hip_bfloat16 As[64 * 32];
    __shared__ __hip_bfloat16 Bs[64 * 32];
    const int bid = blockIdx.x;
    if (bid >= GEMM_BLOCKS) {
        // ---- edge bucketing: 512 blocks x 256 threads x 2 edges = EE exactly ----
        int k = ((bid - GEMM_BLOCKS) * 256 + threadIdx.x) * 2;
        int2 sv = *(const int2*)(src + k);
        int2 tv = *(const int2*)(tgt + k);
        int p = atomicAdd(&cnt[sv.x], 1);
        if (p < CAP) buck[sv.x * CAP + p] = tv.x;
        p = atomicAdd(&cnt[sv.y], 1);
        if (p < CAP) buck[sv.y * CAP + p] = tv.y;
        return;
    }
    const int tid = threadIdx.x;
    const int row0 = (bid >> 2) * 64, col0 = (bid & 3) * 64;
    const int w = tid >> 6, l = tid & 63;
    const int quad = l >> 4, r = l & 15;
    const int mh = (w & 1) * 32, nh = (w >> 1) * 32;
    f32x4 acc[2][2] = {};

    const int srow = tid >> 2, scol = (tid & 3) * 8;
    const float* gA = X + (size_t)(row0 + srow) * DIN + scol;
    const __hip_bfloat16* gB = B + (size_t)(col0 + srow) * DIN + scol;
    __hip_bfloat16* lB = &Bs[tid * 8];

    for (int k0 = 0; k0 < DIN; k0 += 32) {
        float4 a0 = *(const float4*)(gA + k0);
        float4 a1 = *(const float4*)(gA + k0 + 4);
        load16_lds(gB + k0, lB);
        bf16x8 av;
        av[0] = f2bf_bits(a0.x); av[1] = f2bf_bits(a0.y);
        av[2] = f2bf_bits(a0.z); av[3] = f2bf_bits(a0.w);
        av[4] = f2bf_bits(a1.x); av[5] = f2bf_bits(a1.y);
        av[6] = f2bf_bits(a1.z); av[7] = f2bf_bits(a1.w);
        *(bf16x8*)&As[tid * 8] = av;
        __syncthreads();
        bf16x8 aF[2], bF[2];
#pragma unroll
        for (int mi = 0; mi < 2; mi++)
            aF[mi] = *(const bf16x8*)&As[(mh + mi * 16 + r) * 32 + quad * 8];
#pragma unroll
        for (int ni = 0; ni < 2; ni++)
            bF[ni] = *(const bf16x8*)&Bs[(nh + ni * 16 + r) * 32 + quad * 8];
#pragma unroll
        for (int mi = 0; mi < 2; mi++)
#pragma unroll
            for (int ni = 0; ni < 2; ni++)
                acc[mi][ni] = __builtin_amdgcn_mfma_f32_16x16x32_bf16(aF[mi], bF[ni], acc[mi][ni], 0, 0, 0);
        __syncthreads();
    }

#pragma unroll
    for (int mi = 0; mi < 2; mi++)
#pragma unroll
        for (int ni = 0; ni < 2; ni++) {
            int gcol = col0 + nh + ni * 16 + r;
            float bv = bias[gcol];
#pragma unroll
            for (int reg = 0; reg < 4; reg++) {
                int grow = row0 + mh + mi * 16 + quad * 4 + reg;
                Cb[(size_t)grow * HH + gcol] = __float2bfloat16(acc[mi][ni][reg] + bv);
            }
        }
}

// ---------------- layer GEMM + fused score epilogue; C stored as fp8 e4m3 ----------------
__global__ __launch_bounds__(256) void gemm_bb_score(const __hip_bfloat16* __restrict__ A,
                                                     const __hip_bfloat16* __restrict__ B,
                                                     uint8_t* __restrict__ C8,
                                                     const float* __restrict__ ag1,
                                                     const float* __restrict__ ag2,
                                                     float* __restrict__ s1, float* __restrict__ s2,
                                                     float* __restrict__ St,
                                                     int Nc, int K) {
    __shared__ __hip_bfloat16 As[64 * 32];
    __shared__ __hip_bfloat16 Bs[64 * 32];
    const int tid = threadIdx.x;
    const int row0 = blockIdx.y * 64, col0 = blockIdx.x * 64;
    const int w = tid >> 6, l = tid & 63;
    const int quad = l >> 4, r = l & 15;
    const int mh = (w & 1) * 32, nh = (w >> 1) * 32;
    f32x4 acc[2][2] = {};

    const int srow = tid >> 2, scol = (tid & 3) * 8;
    const __hip_bfloat16* gA = A + (size_t)(row0 + srow) * K + scol;
    const __hip_bfloat16* gB = B + (size_t)(col0 + srow) * K + scol;
    __hip_bfloat16* lA = &As[tid * 8];
    __hip_bfloat16* lB = &Bs[tid * 8];

    for (int k0 = 0; k0 < K; k0 += 32) {
        load16_lds(gA + k0, lA);
        load16_lds(gB + k0, lB);
        __syncthreads();
        bf16x8 aF[2], bF[2];
#pragma unroll
        for (int mi = 0; mi < 2; mi++)
            aF[mi] = *(const bf16x8*)&As[(mh + mi * 16 + r) * 32 + quad * 8];
#pragma unroll
        for (int ni = 0; ni < 2; ni++)
            bF[ni] = *(const bf16x8*)&Bs[(nh + ni * 16 + r) * 32 + quad * 8];
#pragma unroll
        for (int mi = 0; mi < 2; mi++)
#pragma unroll
            for (int ni = 0; ni < 2; ni++)
                acc[mi][ni] = __builtin_amdgcn_mfma_f32_16x16x32_bf16(aF[mi], bF[ni], acc[mi][ni], 0, 0, 0);
        __syncthreads();
    }

#pragma unroll
    for (int mi = 0; mi < 2; mi++)
#pragma unroll
        for (int ni = 0; ni < 2; ni++) {
            int gcol = col0 + nh + ni * 16 + r;
#pragma unroll
            for (int reg = 0; reg < 4; reg++) {
                int grow = row0 + mh + mi * 16 + quad * 4 + reg;
                C8[(size_t)grow * Nc + gcol] = f2fp8(acc[mi][ni][reg]);
            }
        }

    float a1v[2], a2v[2];
#pragma unroll
    for (int ni = 0; ni < 2; ni++) {
        int gcol = col0 + nh + ni * 16 + r;
        a1v[ni] = ag1[gcol];
        a2v[ni] = ag2[gcol];
    }
#pragma unroll
    for (int mi = 0; mi < 2; mi++)
#pragma unroll
        for (int reg = 0; reg < 4; reg++) {
            float p1 = acc[mi][0][reg] * a1v[0] + acc[mi][1][reg] * a1v[1];
            float p2 = acc[mi][0][reg] * a2v[0] + acc[mi][1][reg] * a2v[1];
#pragma unroll
            for (int off = 1; off <= 8; off <<= 1) {
                p1 += __shfl_xor(p1, off);
                p2 += __shfl_xor(p2, off);
            }
            if (r == 0) {
                int grow = row0 + mh + mi * 16 + quad * 4 + reg;
                atomicAdd(&s1[grow], p1);
                atomicAdd(&s2[grow], p2);
            }
        }
#pragma unroll
    for (int ni = 0; ni < 2; ni++) {
        float pS = 0.f;
#pragma unroll
        for (int mi = 0; mi < 2; mi++)
#pragma unroll
            for (int reg = 0; reg < 4; reg++) pS += acc[mi][ni][reg];
        pS += __shfl_xor(pS, 16);
        pS += __shfl_xor(pS, 32);
        if (quad == 0) atomicAdd(&St[col0 + nh + ni * 16 + r], pS);
    }
}

// ---------------- wave-per-row GAT (EXACT R4 version: no LDS, gate store, 8-deep batched fp8 gathers) ----------------
// lane = 64 lanes; half = lane>>5 processes even/odd edges; lane owns channels 8*(lane&31)..+7
__global__ __launch_bounds__(256) void gat_row(const __hip_bfloat16* __restrict__ hprev,
                                               const uint8_t* __restrict__ hw8,
                                               const int* __restrict__ cnt, const int* __restrict__ buck,
                                               const float* __restrict__ s1, const float* __restrict__ s2,
                                               const float* __restrict__ St,
                                               const float* __restrict__ lng, const float* __restrict__ lnb,
                                               const float* __restrict__ W_pool, const float* __restrict__ b_pool,
                                               float* __restrict__ houtf, __hip_bfloat16* __restrict__ houtb,
                                               float* __restrict__ gate, int last) {
    const int wv = threadIdx.x >> 6, lane = threadIdx.x & 63;
    const int half = lane >> 5, sl = lane & 31;
    const int i = blockIdx.x * 4 + wv;
    const int deg = min(cnt[i], CAP);
    const int base = i * CAP;
    const float s1i = s1[i];

    float u[8] = {};
    float lsum = 0.f;

    for (int kb = 0; kb < deg; kb += 64) {
        int k = kb + lane;
        float wk = 0.f;
        int ck = 0;
        if (k < deg) {
            int j = buck[base + k];
            float e = s1i + s2[j];
            e = e > 0.f ? e : 0.2f * e;
            wk = __expf(e) - 1.f;
            ck = j;
        }
        lsum += wk;
        int nb = min(64, deg - kb);
        int npair = (nb + 1) >> 1;            // <= 32
        for (int jj = 0; jj < npair; jj += 8) {
            int cj[8];
            float wj[8];
#pragma unroll
            for (int p = 0; p < 8; p++) {
                int e2 = 2 * (jj + p) + half; // <= 63 always
                cj[p] = __shfl(ck, e2);
                wj[p] = __shfl(wk, e2);
            }
            uint2 hv[8];
#pragma unroll
            for (int p = 0; p < 8; p++)
                hv[p] = *(const uint2*)(hw8 + (size_t)cj[p] * HH + 8 * sl);
#pragma unroll
            for (int p = 0; p < 8; p++) {
                float f[8];
                fp8x4_to_f32(hv[p].x, f);
                fp8x4_to_f32(hv[p].y, f + 4);
#pragma unroll
                for (int q = 0; q < 8; q++) u[q] += wj[p] * f[q];
            }
        }
    }
    // combine even/odd halves (each lane pair (sl, sl+32) covers same channels)
#pragma unroll
    for (int q = 0; q < 8; q++) u[q] += __shfl_xor(u[q], 32);
    // lsum over all 64 lanes
#pragma unroll
    for (int off = 32; off; off >>= 1) lsum += __shfl_xor(lsum, off);
    const float inv = 1.f / ((float)NN + lsum);

    float4 Sa = *(const float4*)(St + 8 * sl);
    float4 Sb = *(const float4*)(St + 8 * sl + 4);
    float Sts[8] = { Sa.x, Sa.y, Sa.z, Sa.w, Sb.x, Sb.y, Sb.z, Sb.w };
    bf16x8 hp = *(const bf16x8*)((const short*)hprev + (size_t)i * HH + 8 * sl);
    float x[8];
    float part = 0.f;
#pragma unroll
    for (int q = 0; q < 8; q++) { x[q] = bf2f(hp[q]) + (Sts[q] + u[q]) * inv; part += x[q]; }
    // 32-lane butterfly: each half independently sums all 256 channels
#pragma unroll
    for (int off = 16; off; off >>= 1) part += __shfl_xor(part, off);
    float mu = part * (1.f / HH);
    float d[8];
    float vs = 0.f;
#pragma unroll
    for (int q = 0; q < 8; q++) { d[q] = x[q] - mu; vs += d[q] * d[q]; }
#pragma unroll
    for (int off = 16; off; off >>= 1) vs += __shfl_xor(vs, off);
    float rstd = rsqrtf(vs * (1.f / HH) + LN_EPS);
    float4 ga = *(const float4*)(lng + 8 * sl);
    float4 gb = *(const float4*)(lng + 8 * sl + 4);
    float4 ba = *(const float4*)(lnb + 8 * sl);
    float4 bb = *(const float4*)(lnb + 8 * sl + 4);
    float gg[8] = { ga.x, ga.y, ga.z, ga.w, gb.x, gb.y, gb.z, gb.w };
    float bv[8] = { ba.x, ba.y, ba.z, ba.w, bb.x, bb.y, bb.z, bb.w };
    float y[8];
#pragma unroll
    for (int q = 0; q < 8; q++) {
        float t = d[q] * rstd * gg[q] + bv[q];
        y[q] = t > 0.f ? t : __expf(t) - 1.f;
    }

    // stores: half 0 writes channels [8sl..8sl+3], half 1 writes [8sl+4..8sl+7]
    const int co = 8 * sl + 4 * half;
    if (houtb) {
        s16x4 yv;
#pragma unroll
        for (int q = 0; q < 4; q++) yv[q] = f2bf_bits(y[4 * half + q]);
        *(s16x4*)((short*)houtb + (size_t)i * HH + co) = yv;
    }
    if (houtf) {
        float4 yf = { y[4 * half], y[4 * half + 1], y[4 * half + 2], y[4 * half + 3] };
        *(float4*)(houtf + (size_t)i * HH + co) = yf;
    }

    if (last) {
        float4 wa = *(const float4*)(W_pool + 8 * sl);
        float4 wb = *(const float4*)(W_pool + 8 * sl + 4);
        float wp[8] = { wa.x, wa.y, wa.z, wa.w, wb.x, wb.y, wb.z, wb.w };
        float p = 0.f;
#pragma unroll
        for (int q = 0; q < 8; q++) p += y[q] * wp[q];
#pragma unroll
        for (int off = 16; off; off >>= 1) p += __shfl_xor(p, off);
        if (lane == 0) gate[i] = 1.f / (1.f + __expf(-(p + b_pool[0])));
    }
}

// ---------------- pooling: 256 blocks x 32 rows (256 atomics/address) ----------------
__global__ __launch_bounds__(256) void pool_kernel(const float* __restrict__ h, const float* __restrict__ gate,
                                                   float* __restrict__ emb) {
    int c = threadIdx.x;
    int r0 = blockIdx.x * 32;
    float acc = 0.f;
#pragma unroll
    for (int rr = 0; rr < 32; rr++) {
        int r = r0 + rr;
        acc += gate[r] * h[(size_t)r * HH + c];
    }
    atomicAdd(&emb[c], acc);
}

extern "C" void kernel_launch(void* const* d_in, const int* in_sizes, int n_in,
                              void* d_out, int out_size, void* d_ws, size_t ws_size,
                              hipStream_t stream) {
    const float* X      = (const float*)d_in[0];
    const int*   ei     = (const int*)d_in[1];
    const float* W_in   = (const float*)d_in[2];
    const float* b_in   = (const float*)d_in[3];
    const float* W_gat  = (const float*)d_in[4];
    const float* a_gat  = (const float*)d_in[5];
    const float* ln_g   = (const float*)d_in[6];
    const float* ln_b   = (const float*)d_in[7];
    const float* W_pool = (const float*)d_in[8];
    const float* b_pool = (const float*)d_in[9];
    float* out = (float*)d_out;

    // ws layout: bf16/fp8 region, then zero-init fp32/int block, then gate/buckets
    __hip_bfloat16* hb    = (__hip_bfloat16*)d_ws;            // NN*HH bf16
    uint8_t*        hw8   = (uint8_t*)(hb + (size_t)NN * HH); // NN*HH fp8
    __hip_bfloat16* Wb_in = (__hip_bfloat16*)(hw8 + (size_t)NN * HH); // HH*DIN
    __hip_bfloat16* Wgb   = Wb_in + (size_t)HH * DIN;         // 2*HH*HH
    float* zbase = (float*)(Wgb + (size_t)2 * HH * HH);
    float* s1_0 = zbase;                 // NN
    float* s2_0 = s1_0 + NN;             // NN
    float* St_0 = s2_0 + NN;             // HH
    float* s1_1 = St_0 + HH;             // NN
    float* s2_1 = s1_1 + NN;             // NN
    float* St_1 = s2_1 + NN;             // HH
    int* cnt  = (int*)(St_1 + HH);       // NN  (zeroed in prep)
    float* gate = (float*)(cnt + NN);    // NN
    int* buck = (int*)(gate + NN);       // NN*CAP

    const int* src = ei;
    const int* tgt = ei + EE;
    float* emb = out + (size_t)NN * HH;

    // 1) prep: zero + weight bf16 conversions
    prep<<<256, 256, 0, stream>>>(W_in, Wb_in, W_gat, Wgb, zbase, emb);

    // 2) h = X @ W_in^T + b_in (f32 A reg-staged)  ||  edge bucketing (blocks >= 512)
    gemm_in_fill<<<GEMM_BLOCKS + EE / 512, 256, 0, stream>>>(X, Wb_in, b_in, hb, src, tgt, cnt, buck);

    for (int ll = 0; ll < 2; ll++) {
        float* s1 = ll ? s1_1 : s1_0;
        float* s2 = ll ? s2_1 : s2_0;
        float* St = ll ? St_1 : St_0;
        const float* ag = a_gat + (size_t)ll * 2 * HH;
        // 3/5) hw = h @ W_gat[l]^T (fp8 out) + score partials
        gemm_bb_score<<<dim3(HH / 64, NN / 64), 256, 0, stream>>>(hb, Wgb + (size_t)ll * HH * HH, hw8,
                                                                  ag, ag + HH, s1, s2, St, HH, HH);
        // 4/6) aggregation + LN + ELU (+ gate on last layer)
        gat_row<<<NN / 4, 256, 0, stream>>>(hb, hw8, cnt, buck, s1, s2, St,
                                            ln_g + (size_t)ll * HH, ln_b + (size_t)ll * HH,
                                            W_pool, b_pool,
                                            (ll == 1) ? out : nullptr,
                                            (ll == 0) ? hb : nullptr,
                                            gate, ll);
    }

    // 7) gated pooling
    pool_kernel<<<NN / 32, 256, 0, stream>>>(out, gate, emb);
}

// Round 10
// 168.720 us; speedup vs baseline: 1.2144x; 1.0036x over previous
//
#include <hip/hip_runtime.h>
#include <hip/hip_bf16.h>
#include <stdint.h>
#include <math.h>

#define NN 8192
#define DIN 512
#define HH 256
#define EE 262144
#define CAP 96
#define LN_EPS 1e-5f

typedef __attribute__((ext_vector_type(8))) short bf16x8;
typedef __attribute__((ext_vector_type(4))) short s16x4;
typedef __attribute__((ext_vector_type(4))) float f32x4;
typedef __attribute__((ext_vector_type(2))) float f32x2;

#if defined(__has_builtin)
#if __has_builtin(__builtin_amdgcn_cvt_pk_f32_fp8) && __has_builtin(__builtin_amdgcn_cvt_pk_fp8_f32)
#define HAVE_FP8_CVT 1
#endif
#endif

__device__ __forceinline__ short f2bf_bits(float x) {
    __hip_bfloat16 b = __float2bfloat16(x);
    return __builtin_bit_cast(short, b);
}
__device__ __forceinline__ float bf2f(short s) {
    uint32_t u = ((uint32_t)(uint16_t)s) << 16;
    return __builtin_bit_cast(float, u);
}
__device__ __forceinline__ void load16_lds(const void* g, void* l) {
    __builtin_amdgcn_global_load_lds((const __attribute__((address_space(1))) uint32_t*)g,
                                     (__attribute__((address_space(3))) uint32_t*)l, 16, 0, 0);
}

// ---- fp8 e4m3 (OCP) encode/decode: HW cvt on gfx950, software fallback otherwise ----
__device__ __forceinline__ uint8_t f2fp8(float x) {
#ifdef HAVE_FP8_CVT
    uint32_t p = __builtin_amdgcn_cvt_pk_fp8_f32(x, 0.f, 0u, false);
    return (uint8_t)(p & 0xFF);
#else
    uint8_t s = (x < 0.f) ? 0x80 : 0;
    float a = fabsf(x);
    if (!(a == a)) return 0x7F;
    if (a >= 448.f) return s | 0x7E;
    if (a < 0.0009765625f) return s;
    int e; float mf = frexpf(a, &e);
    int E = e + 6;
    if (E <= 0) { int q = (int)(a * 512.f + 0.5f); if (q >= 8) return s | 0x08; return s | (uint8_t)q; }
    int q = (int)(mf * 16.f + 0.5f);
    if (q >= 16) { q = 8; E++; }
    if (E > 15 || (E == 15 && q - 8 > 6)) return s | 0x7E;
    return s | (uint8_t)((E << 3) | (q - 8));
#endif
}
__device__ __forceinline__ void fp8x4_to_f32(uint32_t w, float* f) {
#ifdef HAVE_FP8_CVT
    f32x2 a = __builtin_amdgcn_cvt_pk_f32_fp8(w, false);
    f32x2 b = __builtin_amdgcn_cvt_pk_f32_fp8(w, true);
    f[0] = a[0]; f[1] = a[1]; f[2] = b[0]; f[3] = b[1];
#else
#pragma unroll
    for (int i = 0; i < 4; i++) {
        uint8_t bb = (w >> (8 * i)) & 0xFF;
        int s = bb >> 7, e = (bb >> 3) & 15, m = bb & 7;
        float v = e ? ldexpf((float)(8 + m), e - 10) : ldexpf((float)m, -9);
        f[i] = s ? -v : v;
    }
#endif
}

// ---------------- prep: zero accumulators/cnt/emb, convert W_in/W_gat to bf16 ----------------
// X is NOT converted here -- the input GEMM reg-stages f32 X directly (saves 24 MB).
#define NW1 (HH * DIN)
#define NW2 (2 * HH * HH)
#define ZCOUNT (2 * (2 * NN + HH) + NN)   // s1/s2/St x2 layers + cnt
__global__ __launch_bounds__(256) void prep(const float* __restrict__ W_in, __hip_bfloat16* __restrict__ Wb_in,
                                            const float* __restrict__ W_gat, __hip_bfloat16* __restrict__ Wgb,
                                            float* __restrict__ zbase, float* __restrict__ emb) {
    int gtid = blockIdx.x * 256 + threadIdx.x;   // grid = 256 blocks -> 65536 threads
    if (gtid < ZCOUNT) ((int*)zbase)[gtid] = 0;
    if (gtid < HH) emb[gtid] = 0.f;
    int q = gtid * 4;                            // q < NW1+NW2 = 262144 for all threads
    const float* x;
    __hip_bfloat16* y;
    int b;
    if (q < NW1) { x = W_in; y = Wb_in; b = q; }
    else { x = W_gat; y = Wgb; b = q - NW1; }
    float4 v = *(const float4*)(x + b);
    s16x4 s = { f2bf_bits(v.x), f2bf_bits(v.y), f2bf_bits(v.z), f2bf_bits(v.w) };
    *(s16x4*)((short*)y + b) = s;
}

// ---------------- merged: input GEMM (h = X @ W_in^T + b_in, f32 A reg-staged) + edge bucketing ----------------
#define GEMM_BLOCKS 512   // (HH/64) x (NN/64) = 4 x 128
__global__ __launch_bounds__(256) void gemm_in_fill(const float* __restrict__ X,
                                                    const __hip_bfloat16* __restrict__ B,
                                                    const float* __restrict__ bias,
                                                    __hip_bfloat16* __restrict__ Cb,
                                                    const int* __restrict__ src, const int* __restrict__ tgt,
                                                    int* __restrict__ cnt, int* __restrict__ buck) {
    __shared__ __hip_bfloat16 As[64 * 32];
    __shared__ __hip_bfloat16 Bs[64 * 32];
    const int bid = blockIdx.x;
    if (bid >= GEMM_BLOCKS) {
        // ---- edge bucketing: 512 blocks x 256 threads x 2 edges = EE exactly ----
        int k = ((bid - GEMM_BLOCKS) * 256 + threadIdx.x) * 2;
        int2 sv = *(const int2*)(src + k);
        int2 tv = *(const int2*)(tgt + k);
        int p = atomicAdd(&cnt[sv.x], 1);
        if (p < CAP) buck[sv.x * CAP + p] = tv.x;
        p = atomicAdd(&cnt[sv.y], 1);
        if (p < CAP) buck[sv.y * CAP + p] = tv.y;
        return;
    }
    const int tid = threadIdx.x;
    const int row0 = (bid >> 2) * 64, col0 = (bid & 3) * 64;
    const int w = tid >> 6, l = tid & 63;
    const int quad = l >> 4, r = l & 15;
    const int mh = (w & 1) * 32, nh = (w >> 1) * 32;
    f32x4 acc[2][2] = {};

    const int srow = tid >> 2, scol = (tid & 3) * 8;
    const float* gA = X + (size_t)(row0 + srow) * DIN + scol;
    const __hip_bfloat16* gB = B + (size_t)(col0 + srow) * DIN + scol;
    __hip_bfloat16* lB = &Bs[tid * 8];

    for (int k0 = 0; k0 < DIN; k0 += 32) {
        float4 a0 = *(const float4*)(gA + k0);
        float4 a1 = *(const float4*)(gA + k0 + 4);
        load16_lds(gB + k0, lB);
        bf16x8 av;
        av[0] = f2bf_bits(a0.x); av[1] = f2bf_bits(a0.y);
        av[2] = f2bf_bits(a0.z); av[3] = f2bf_bits(a0.w);
        av[4] = f2bf_bits(a1.x); av[5] = f2bf_bits(a1.y);
        av[6] = f2bf_bits(a1.z); av[7] = f2bf_bits(a1.w);
        *(bf16x8*)&As[tid * 8] = av;
        __syncthreads();
        bf16x8 aF[2], bF[2];
#pragma unroll
        for (int mi = 0; mi < 2; mi++)
            aF[mi] = *(const bf16x8*)&As[(mh + mi * 16 + r) * 32 + quad * 8];
#pragma unroll
        for (int ni = 0; ni < 2; ni++)
            bF[ni] = *(const bf16x8*)&Bs[(nh + ni * 16 + r) * 32 + quad * 8];
#pragma unroll
        for (int mi = 0; mi < 2; mi++)
#pragma unroll
            for (int ni = 0; ni < 2; ni++)
                acc[mi][ni] = __builtin_amdgcn_mfma_f32_16x16x32_bf16(aF[mi], bF[ni], acc[mi][ni], 0, 0, 0);
        __syncthreads();
    }

#pragma unroll
    for (int mi = 0; mi < 2; mi++)
#pragma unroll
        for (int ni = 0; ni < 2; ni++) {
            int gcol = col0 + nh + ni * 16 + r;
            float bv = bias[gcol];
#pragma unroll
            for (int reg = 0; reg < 4; reg++) {
                int grow = row0 + mh + mi * 16 + quad * 4 + reg;
                Cb[(size_t)grow * HH + gcol] = __float2bfloat16(acc[mi][ni][reg] + bv);
            }
        }
}

// ---------------- layer GEMM + fused score epilogue; C stored as fp8 e4m3 ----------------
__global__ __launch_bounds__(256) void gemm_bb_score(const __hip_bfloat16* __restrict__ A,
                                                     const __hip_bfloat16* __restrict__ B,
                                                     uint8_t* __restrict__ C8,
                                                     const float* __restrict__ ag1,
                                                     const float* __restrict__ ag2,
                                                     float* __restrict__ s1, float* __restrict__ s2,
                                                     float* __restrict__ St,
                                                     int Nc, int K) {
    __shared__ __hip_bfloat16 As[64 * 32];
    __shared__ __hip_bfloat16 Bs[64 * 32];
    const int tid = threadIdx.x;
    const int row0 = blockIdx.y * 64, col0 = blockIdx.x * 64;
    const int w = tid >> 6, l = tid & 63;
    const int quad = l >> 4, r = l & 15;
    const int mh = (w & 1) * 32, nh = (w >> 1) * 32;
    f32x4 acc[2][2] = {};

    const int srow = tid >> 2, scol = (tid & 3) * 8;
    const __hip_bfloat16* gA = A + (size_t)(row0 + srow) * K + scol;
    const __hip_bfloat16* gB = B + (size_t)(col0 + srow) * K + scol;
    __hip_bfloat16* lA = &As[tid * 8];
    __hip_bfloat16* lB = &Bs[tid * 8];

    for (int k0 = 0; k0 < K; k0 += 32) {
        load16_lds(gA + k0, lA);
        load16_lds(gB + k0, lB);
        __syncthreads();
        bf16x8 aF[2], bF[2];
#pragma unroll
        for (int mi = 0; mi < 2; mi++)
            aF[mi] = *(const bf16x8*)&As[(mh + mi * 16 + r) * 32 + quad * 8];
#pragma unroll
        for (int ni = 0; ni < 2; ni++)
            bF[ni] = *(const bf16x8*)&Bs[(nh + ni * 16 + r) * 32 + quad * 8];
#pragma unroll
        for (int mi = 0; mi < 2; mi++)
#pragma unroll
            for (int ni = 0; ni < 2; ni++)
                acc[mi][ni] = __builtin_amdgcn_mfma_f32_16x16x32_bf16(aF[mi], bF[ni], acc[mi][ni], 0, 0, 0);
        __syncthreads();
    }

#pragma unroll
    for (int mi = 0; mi < 2; mi++)
#pragma unroll
        for (int ni = 0; ni < 2; ni++) {
            int gcol = col0 + nh + ni * 16 + r;
#pragma unroll
            for (int reg = 0; reg < 4; reg++) {
                int grow = row0 + mh + mi * 16 + quad * 4 + reg;
                C8[(size_t)grow * Nc + gcol] = f2fp8(acc[mi][ni][reg]);
            }
        }

    float a1v[2], a2v[2];
#pragma unroll
    for (int ni = 0; ni < 2; ni++) {
        int gcol = col0 + nh + ni * 16 + r;
        a1v[ni] = ag1[gcol];
        a2v[ni] = ag2[gcol];
    }
#pragma unroll
    for (int mi = 0; mi < 2; mi++)
#pragma unroll
        for (int reg = 0; reg < 4; reg++) {
            float p1 = acc[mi][0][reg] * a1v[0] + acc[mi][1][reg] * a1v[1];
            float p2 = acc[mi][0][reg] * a2v[0] + acc[mi][1][reg] * a2v[1];
#pragma unroll
            for (int off = 1; off <= 8; off <<= 1) {
                p1 += __shfl_xor(p1, off);
                p2 += __shfl_xor(p2, off);
            }
            if (r == 0) {
                int grow = row0 + mh + mi * 16 + quad * 4 + reg;
                atomicAdd(&s1[grow], p1);
                atomicAdd(&s2[grow], p2);
            }
        }
#pragma unroll
    for (int ni = 0; ni < 2; ni++) {
        float pS = 0.f;
#pragma unroll
        for (int mi = 0; mi < 2; mi++)
#pragma unroll
            for (int reg = 0; reg < 4; reg++) pS += acc[mi][ni][reg];
        pS += __shfl_xor(pS, 16);
        pS += __shfl_xor(pS, 32);
        if (quad == 0) atomicAdd(&St[col0 + nh + ni * 16 + r], pS);
    }
}

// ---------------- wave-per-row GAT (lean R4 version: no LDS, gate store, 8-deep batched fp8 gathers) ----------------
// lane = 64 lanes; half = lane>>5 processes even/odd edges; lane owns channels 8*(lane&31)..+7
__global__ __launch_bounds__(256) void gat_row(const __hip_bfloat16* __restrict__ hprev,
                                               const uint8_t* __restrict__ hw8,
                                               const int* __restrict__ cnt, const int* __restrict__ buck,
                                               const float* __restrict__ s1, const float* __restrict__ s2,
                                               const float* __restrict__ St,
                                               const float* __restrict__ lng, const float* __restrict__ lnb,
                                               const float* __restrict__ W_pool, const float* __restrict__ b_pool,
                                               float* __restrict__ houtf, __hip_bfloat16* __restrict__ houtb,
                                               float* __restrict__ gate, int last) {
    const int wv = threadIdx.x >> 6, lane = threadIdx.x & 63;
    const int half = lane >> 5, sl = lane & 31;
    const int i = blockIdx.x * 4 + wv;
    const int deg = min(cnt[i], CAP);
    const int base = i * CAP;
    const float s1i = s1[i];

    float u[8] = {};
    float lsum = 0.f;

    for (int kb = 0; kb < deg; kb += 64) {
        int k = kb + lane;
        float wk = 0.f;
        int ck = 0;
        if (k < deg) {
            int j = buck[base + k];
            float e = s1i + s2[j];
            e = e > 0.f ? e : 0.2f * e;
            wk = __expf(e) - 1.f;
            ck = j;
        }
        lsum += wk;
        int nb = min(64, deg - kb);
        int npair = (nb + 1) >> 1;            // <= 32
        for (int jj = 0; jj < npair; jj += 8) {
            int cj[8];
            float wj[8];
#pragma unroll
            for (int p = 0; p < 8; p++) {
                int e2 = 2 * (jj + p) + half; // <= 63 always
                cj[p] = __shfl(ck, e2);
                wj[p] = __shfl(wk, e2);
            }
            uint2 hv[8];
#pragma unroll
            for (int p = 0; p < 8; p++)
                hv[p] = *(const uint2*)(hw8 + (size_t)cj[p] * HH + 8 * sl);
#pragma unroll
            for (int p = 0; p < 8; p++) {
                float f[8];
                fp8x4_to_f32(hv[p].x, f);
                fp8x4_to_f32(hv[p].y, f + 4);
#pragma unroll
                for (int q = 0; q < 8; q++) u[q] += wj[p] * f[q];
            }
        }
    }
    // combine even/odd halves (each lane pair (sl, sl+32) covers same channels)
#pragma unroll
    for (int q = 0; q < 8; q++) u[q] += __shfl_xor(u[q], 32);
    // lsum over all 64 lanes
#pragma unroll
    for (int off = 32; off; off >>= 1) lsum += __shfl_xor(lsum, off);
    const float inv = 1.f / ((float)NN + lsum);

    float4 Sa = *(const float4*)(St + 8 * sl);
    float4 Sb = *(const float4*)(St + 8 * sl + 4);
    float Sts[8] = { Sa.x, Sa.y, Sa.z, Sa.w, Sb.x, Sb.y, Sb.z, Sb.w };
    bf16x8 hp = *(const bf16x8*)((const short*)hprev + (size_t)i * HH + 8 * sl);
    float x[8];
    float part = 0.f;
#pragma unroll
    for (int q = 0; q < 8; q++) { x[q] = bf2f(hp[q]) + (Sts[q] + u[q]) * inv; part += x[q]; }
    // 32-lane butterfly: each half independently sums all 256 channels
#pragma unroll
    for (int off = 16; off; off >>= 1) part += __shfl_xor(part, off);
    float mu = part * (1.f / HH);
    float d[8];
    float vs = 0.f;
#pragma unroll
    for (int q = 0; q < 8; q++) { d[q] = x[q] - mu; vs += d[q] * d[q]; }
#pragma unroll
    for (int off = 16; off; off >>= 1) vs += __shfl_xor(vs, off);
    float rstd = rsqrtf(vs * (1.f / HH) + LN_EPS);
    float4 ga = *(const float4*)(lng + 8 * sl);
    float4 gb = *(const float4*)(lng + 8 * sl + 4);
    float4 ba = *(const float4*)(lnb + 8 * sl);
    float4 bb = *(const float4*)(lnb + 8 * sl + 4);
    float gg[8] = { ga.x, ga.y, ga.z, ga.w, gb.x, gb.y, gb.z, gb.w };
    float bv[8] = { ba.x, ba.y, ba.z, ba.w, bb.x, bb.y, bb.z, bb.w };
    float y[8];
#pragma unroll
    for (int q = 0; q < 8; q++) {
        float t = d[q] * rstd * gg[q] + bv[q];
        y[q] = t > 0.f ? t : __expf(t) - 1.f;
    }

    // stores: half 0 writes channels [8sl..8sl+3], half 1 writes [8sl+4..8sl+7]
    const int co = 8 * sl + 4 * half;
    if (houtb) {
        s16x4 yv;
#pragma unroll
        for (int q = 0; q < 4; q++) yv[q] = f2bf_bits(y[4 * half + q]);
        *(s16x4*)((short*)houtb + (size_t)i * HH + co) = yv;
    }
    if (houtf) {
        float4 yf = { y[4 * half], y[4 * half + 1], y[4 * half + 2], y[4 * half + 3] };
        *(float4*)(houtf + (size_t)i * HH + co) = yf;
    }

    if (last) {
        float4 wa = *(const float4*)(W_pool + 8 * sl);
        float4 wb = *(const float4*)(W_pool + 8 * sl + 4);
        float wp[8] = { wa.x, wa.y, wa.z, wa.w, wb.x, wb.y, wb.z, wb.w };
        float p = 0.f;
#pragma unroll
        for (int q = 0; q < 8; q++) p += y[q] * wp[q];
#pragma unroll
        for (int off = 16; off; off >>= 1) p += __shfl_xor(p, off);
        if (lane == 0) gate[i] = 1.f / (1.f + __expf(-(p + b_pool[0])));
    }
}

// ---------------- pooling: 256 blocks x 32 rows (256 atomics/address) ----------------
__global__ __launch_bounds__(256) void pool_kernel(const float* __restrict__ h, const float* __restrict__ gate,
                                                   float* __restrict__ emb) {
    int c = threadIdx.x;
    int r0 = blockIdx.x * 32;
    float acc = 0.f;
#pragma unroll
    for (int rr = 0; rr < 32; rr++) {
        int r = r0 + rr;
        acc += gate[r] * h[(size_t)r * HH + c];
    }
    atomicAdd(&emb[c], acc);
}

extern "C" void kernel_launch(void* const* d_in, const int* in_sizes, int n_in,
                              void* d_out, int out_size, void* d_ws, size_t ws_size,
                              hipStream_t stream) {
    const float* X      = (const float*)d_in[0];
    const int*   ei     = (const int*)d_in[1];
    const float* W_in   = (const float*)d_in[2];
    const float* b_in   = (const float*)d_in[3];
    const float* W_gat  = (const float*)d_in[4];
    const float* a_gat  = (const float*)d_in[5];
    const float* ln_g   = (const float*)d_in[6];
    const float* ln_b   = (const float*)d_in[7];
    const float* W_pool = (const float*)d_in[8];
    const float* b_pool = (const float*)d_in[9];
    float* out = (float*)d_out;

    // ws layout: bf16/fp8 region, then zero-init fp32/int block, then gate/buckets
    __hip_bfloat16* hb    = (__hip_bfloat16*)d_ws;            // NN*HH bf16
    uint8_t*        hw8   = (uint8_t*)(hb + (size_t)NN * HH); // NN*HH fp8
    __hip_bfloat16* Wb_in = (__hip_bfloat16*)(hw8 + (size_t)NN * HH); // HH*DIN
    __hip_bfloat16* Wgb   = Wb_in + (size_t)HH * DIN;         // 2*HH*HH
    float* zbase = (float*)(Wgb + (size_t)2 * HH * HH);
    float* s1_0 = zbase;                 // NN
    float* s2_0 = s1_0 + NN;             // NN
    float* St_0 = s2_0 + NN;             // HH
    float* s1_1 = St_0 + HH;             // NN
    float* s2_1 = s1_1 + NN;             // NN
    float* St_1 = s2_1 + NN;             // HH
    int* cnt  = (int*)(St_1 + HH);       // NN  (zeroed in prep)
    float* gate = (float*)(cnt + NN);    // NN
    int* buck = (int*)(gate + NN);       // NN*CAP

    const int* src = ei;
    const int* tgt = ei + EE;
    float* emb = out + (size_t)NN * HH;

    // 1) prep: zero + weight bf16 conversions
    prep<<<256, 256, 0, stream>>>(W_in, Wb_in, W_gat, Wgb, zbase, emb);

    // 2) h = X @ W_in^T + b_in (f32 A reg-staged)  ||  edge bucketing (blocks >= 512)
    gemm_in_fill<<<GEMM_BLOCKS + EE / 512, 256, 0, stream>>>(X, Wb_in, b_in, hb, src, tgt, cnt, buck);

    for (int ll = 0; ll < 2; ll++) {
        float* s1 = ll ? s1_1 : s1_0;
        float* s2 = ll ? s2_1 : s2_0;
        float* St = ll ? St_1 : St_0;
        const float* ag = a_gat + (size_t)ll * 2 * HH;
        // 3/5) hw = h @ W_gat[l]^T (fp8 out) + score partials
        gemm_bb_score<<<dim3(HH / 64, NN / 64), 256, 0, stream>>>(hb, Wgb + (size_t)ll * HH * HH, hw8,
                                                                  ag, ag + HH, s1, s2, St, HH, HH);
        // 4/6) aggregation + LN + ELU (+ gate on last layer)
        gat_row<<<NN / 4, 256, 0, stream>>>(hb, hw8, cnt, buck, s1, s2, St,
                                            ln_g + (size_t)ll * HH, ln_b + (size_t)ll * HH,
                                            W_pool, b_pool,
                                            (ll == 1) ? out : nullptr,
                                            (ll == 0) ? hb : nullptr,
                                            gate, ll);
    }

    // 7) gated pooling
    pool_kernel<<<NN / 32, 256, 0, stream>>>(out, gate, emb);
}